// Round 4
// baseline (5172.292 us; speedup 1.0000x reference)
//
#include <hip/hip_runtime.h>
#include <hip/hip_bf16.h>
#include <math.h>

typedef unsigned short u16;
typedef unsigned int u32;
typedef short bf16x8 __attribute__((ext_vector_type(8)));
typedef short s16x4 __attribute__((ext_vector_type(4)));
typedef float f32x4 __attribute__((ext_vector_type(4)));

#define DEV static __device__ __forceinline__

constexpr int D = 768;
constexpr int HH = 12;
constexpr int KD = 64;
constexpr int T = 64;
constexpr int NSEQ = 512;
constexpr int MROWS = NSEQ * T;   // 32768
constexpr int DFF = 3072;
constexpr int PP = 16;

DEV float bfr2f(u16 u){ union{u32 i; float f;} c; c.i = ((u32)u) << 16; return c.f; }
DEV u16 f2bfr(float f){
  union{float f; u32 i;} c; c.f = f;
  u32 r = c.i + 0x7FFFu + ((c.i >> 16) & 1u);   // round-nearest-even
  return (u16)(r >> 16);
}

// ---------------- transpose fp32 [R][C] -> bf16 [C][R] (single) ----------------
__global__ __launch_bounds__(256) void k_transpose(const float* __restrict__ W, u16* __restrict__ WT,
                                                   int R, int C){
  __shared__ float tile[32][33];
  int c0 = blockIdx.x * 32, r0 = blockIdx.y * 32;
  int tx = threadIdx.x, ty = threadIdx.y;
  #pragma unroll
  for (int i = 0; i < 32; i += 8)
    tile[ty + i][tx] = W[(size_t)(r0 + ty + i) * C + (c0 + tx)];
  __syncthreads();
  #pragma unroll
  for (int i = 0; i < 32; i += 8)
    WT[(size_t)(c0 + ty + i) * R + (r0 + tx)] = f2bfr(tile[tx][ty + i]);
}

// ---------------- transpose fp32 [R][C] -> split bf16 hi/lo [C][R] ----------------
__global__ __launch_bounds__(256) void k_transpose2(const float* __restrict__ W, u16* __restrict__ WTh,
                                                    u16* __restrict__ WTl, int R, int C){
  __shared__ float tile[32][33];
  int c0 = blockIdx.x * 32, r0 = blockIdx.y * 32;
  int tx = threadIdx.x, ty = threadIdx.y;
  #pragma unroll
  for (int i = 0; i < 32; i += 8)
    tile[ty + i][tx] = W[(size_t)(r0 + ty + i) * C + (c0 + tx)];
  __syncthreads();
  #pragma unroll
  for (int i = 0; i < 32; i += 8){
    float v = tile[tx][ty + i];
    u16 hi = f2bfr(v);
    float rem = v - bfr2f(hi);
    size_t o = (size_t)(c0 + ty + i) * R + (r0 + tx);
    WTh[o] = hi;
    WTl[o] = f2bfr(rem);
  }
}

// ---------------- positional embedding [T][D] ----------------
__global__ void k_pe(float* __restrict__ pe){
  int idx = blockIdx.x * 256 + threadIdx.x;
  if (idx >= T * D) return;
  int t = idx / D, d = idx % D;
  float dv = __expf((float)(d & ~1) * (-9.210340371976184f / (float)D));
  float ang = (float)t * dv;
  pe[idx] = (d & 1) ? cosf(ang) : sinf(ang);
}

// ---------------- patch embedding: h = patches @ W_patch + b + pe ----------------
__global__ __launch_bounds__(256) void k_patch(const float* __restrict__ x, const float* __restrict__ Wp,
                                               const float* __restrict__ bp, const float* __restrict__ pe,
                                               float* __restrict__ h){
  int row = blockIdx.x, t = row & (T - 1);
  __shared__ float xs[PP];
  if (threadIdx.x < PP) xs[threadIdx.x] = x[(size_t)row * PP + threadIdx.x];
  __syncthreads();
  #pragma unroll
  for (int j = 0; j < 3; j++){
    int d = threadIdx.x + j * 256;
    float acc = bp[d] + pe[t * D + d];
    #pragma unroll
    for (int p = 0; p < PP; p++) acc += xs[p] * Wp[p * D + d];
    h[(size_t)row * D + d] = acc;
  }
}

// ---------------- layernorm fp32 -> fp32 ----------------
__global__ __launch_bounds__(256) void k_ln(const float* __restrict__ X, const float* __restrict__ g,
                                            const float* __restrict__ b, float* __restrict__ out){
  int lane = threadIdx.x & 63;
  int row = blockIdx.x * 4 + (threadIdx.x >> 6);
  const float* xr = X + (size_t)row * D;
  float v[12], s = 0.f, sq = 0.f;
  #pragma unroll
  for (int j = 0; j < 12; j++){ v[j] = xr[lane + j * 64]; s += v[j]; sq += v[j] * v[j]; }
  #pragma unroll
  for (int o = 32; o; o >>= 1){ s += __shfl_xor(s, o); sq += __shfl_xor(sq, o); }
  float mean = s * (1.f / 768.f);
  float rstd = rsqrtf(sq * (1.f / 768.f) - mean * mean + 1e-5f);
  float* orow = out + (size_t)row * D;
  #pragma unroll
  for (int j = 0; j < 12; j++){
    int d = lane + j * 64;
    orow[d] = (v[j] - mean) * rstd * g[d] + b[d];
  }
}

// ---------------- split-bf16 GEMM (fp32-accurate): out = act( lerp(A) @ W^T + bias ) ----------------
// A fp32 [M][Kd]; W pre-split bf16 hi/lo planes [Nc][Kd]. 3-product compensation:
// A@W ~= Ah@Wh + Al@Wh + Ah@Wl. ACT: 0 none, 1 exp(-exp(x+b)), 2 sigmoid(x+b). fp32 out.
template<int ACT>
__global__ __launch_bounds__(256) void k_gemm_split(const float* __restrict__ A, const u16* __restrict__ BTh,
                                                    const u16* __restrict__ BTl, const float* __restrict__ mu,
                                                    const float* __restrict__ bias, float* __restrict__ outp,
                                                    int Kd, int Nc){
  __shared__ __align__(16) u16 Ah[128][40];
  __shared__ __align__(16) u16 Al[128][40];
  __shared__ __align__(16) u16 Bh[128][40];
  __shared__ __align__(16) u16 Bl[128][40];
  int tid = threadIdx.x;
  int m0 = blockIdx.x * 128, n0 = blockIdx.y * 128;
  int wv = tid >> 6, lane = tid & 63;
  int wr = (wv >> 1) * 64, wc = (wv & 1) * 64;
  int lr = lane & 15, kg = (lane >> 4) * 8;
  f32x4 acc[4][4] = {};

  for (int k0 = 0; k0 < Kd; k0 += 32){
    __syncthreads();
    #pragma unroll
    for (int pass = 0; pass < 4; pass++){
      int c = pass * 256 + tid;
      int rr = c >> 3, c4 = (c & 7) * 4;
      const float* srcA = A + (size_t)(m0 + rr) * Kd + k0 + c4;
      float4 cur = *(const float4*)srcA;
      if (mu){
        bool tnz = ((m0 + rr) & (T - 1)) != 0;
        float4 prv = tnz ? *(const float4*)(srcA - Kd) : make_float4(0.f, 0.f, 0.f, 0.f);
        float* cf = (float*)&cur; float* pf = (float*)&prv;
        #pragma unroll
        for (int j = 0; j < 4; j++){
          float m = mu[k0 + c4 + j];
          cf[j] = cf[j] + (pf[j] - cf[j]) * m;
        }
      }
      float* cf = (float*)&cur;
      s16x4 ph, pl;
      #pragma unroll
      for (int j = 0; j < 4; j++){
        u16 hi = f2bfr(cf[j]);
        ph[j] = (short)hi;
        pl[j] = (short)f2bfr(cf[j] - bfr2f(hi));
      }
      *(s16x4*)&Ah[rr][c4] = ph;
      *(s16x4*)&Al[rr][c4] = pl;
    }
    #pragma unroll
    for (int pass = 0; pass < 2; pass++){
      int c = pass * 256 + tid;
      int rr = c >> 2, c8 = (c & 3) * 8;
      size_t o = (size_t)(n0 + rr) * Kd + k0 + c8;
      *(uint4*)&Bh[rr][c8] = *(const uint4*)(BTh + o);
      *(uint4*)&Bl[rr][c8] = *(const uint4*)(BTl + o);
    }
    __syncthreads();
    bf16x8 ah[4], al[4], bh[4], bl[4];
    #pragma unroll
    for (int mi = 0; mi < 4; mi++){
      ah[mi] = *(const bf16x8*)&Ah[wr + mi * 16 + lr][kg];
      al[mi] = *(const bf16x8*)&Al[wr + mi * 16 + lr][kg];
    }
    #pragma unroll
    for (int ni = 0; ni < 4; ni++){
      bh[ni] = *(const bf16x8*)&Bh[wc + ni * 16 + lr][kg];
      bl[ni] = *(const bf16x8*)&Bl[wc + ni * 16 + lr][kg];
    }
    #pragma unroll
    for (int mi = 0; mi < 4; mi++){
      #pragma unroll
      for (int ni = 0; ni < 4; ni++){
        acc[mi][ni] = __builtin_amdgcn_mfma_f32_16x16x32_bf16(ah[mi], bh[ni], acc[mi][ni], 0, 0, 0);
        acc[mi][ni] = __builtin_amdgcn_mfma_f32_16x16x32_bf16(al[mi], bh[ni], acc[mi][ni], 0, 0, 0);
        acc[mi][ni] = __builtin_amdgcn_mfma_f32_16x16x32_bf16(ah[mi], bl[ni], acc[mi][ni], 0, 0, 0);
      }
    }
  }

  int rowb = m0 + wr + (lane >> 4) * 4;
  int colb = n0 + wc + lr;
  #pragma unroll
  for (int mi = 0; mi < 4; mi++){
    #pragma unroll
    for (int ni = 0; ni < 4; ni++){
      int gcol = colb + ni * 16;
      float bv = ((ACT == 1 || ACT == 2) && bias) ? bias[gcol] : 0.f;
      #pragma unroll
      for (int i = 0; i < 4; i++){
        int grow = rowb + mi * 16 + i;
        float xv = acc[mi][ni][i] + bv;
        size_t o = (size_t)grow * Nc + gcol;
        if (ACT == 0)      outp[o] = xv;
        else if (ACT == 1) outp[o] = __expf(-__expf(xv));
        else               outp[o] = 1.f / (1.f + __expf(-xv));
      }
    }
  }
}

// ---------------- single-bf16 GEMM: out = act( lerp(A) @ BT^T ) ----------------
// AF32: A fp32 (round once at staging) else A bf16.
// ACT: 3 relu^2->bf16, 4 add->fp32 outF
template<int ACT, bool AF32>
__global__ __launch_bounds__(256) void k_gemm(const void* __restrict__ A, const u16* __restrict__ BT,
                                              const float* __restrict__ mu, void* __restrict__ outp,
                                              float* __restrict__ outF, int Kd, int Nc){
  __shared__ __align__(16) u16 As[128][40];
  __shared__ __align__(16) u16 Bs[128][40];
  int tid = threadIdx.x;
  int m0 = blockIdx.x * 128, n0 = blockIdx.y * 128;
  int wv = tid >> 6, lane = tid & 63;
  int wr = (wv >> 1) * 64, wc = (wv & 1) * 64;
  int lr = lane & 15, kg = (lane >> 4) * 8;
  f32x4 acc[4][4] = {};

  for (int k0 = 0; k0 < Kd; k0 += 32){
    __syncthreads();
    if (AF32){
      const float* Af = (const float*)A;
      #pragma unroll
      for (int pass = 0; pass < 4; pass++){
        int c = pass * 256 + tid;
        int rr = c >> 3, c4 = (c & 7) * 4;
        const float* srcA = Af + (size_t)(m0 + rr) * Kd + k0 + c4;
        float4 cur = *(const float4*)srcA;
        if (mu){
          bool tnz = ((m0 + rr) & (T - 1)) != 0;
          float4 prv = tnz ? *(const float4*)(srcA - Kd) : make_float4(0.f, 0.f, 0.f, 0.f);
          float* cf = (float*)&cur; float* pf = (float*)&prv;
          #pragma unroll
          for (int j = 0; j < 4; j++){
            float m = mu[k0 + c4 + j];
            cf[j] = cf[j] + (pf[j] - cf[j]) * m;
          }
        }
        float* cf = (float*)&cur;
        s16x4 pk;
        #pragma unroll
        for (int j = 0; j < 4; j++) pk[j] = (short)f2bfr(cf[j]);
        *(s16x4*)&As[rr][c4] = pk;
      }
    } else {
      const u16* Ab = (const u16*)A;
      #pragma unroll
      for (int pass = 0; pass < 2; pass++){
        int c = pass * 256 + tid;
        int rr = c >> 2, c8 = (c & 3) * 8;
        *(uint4*)&As[rr][c8] = *(const uint4*)(Ab + (size_t)(m0 + rr) * Kd + k0 + c8);
      }
    }
    #pragma unroll
    for (int pass = 0; pass < 2; pass++){
      int c = pass * 256 + tid;
      int rr = c >> 2, c8 = (c & 3) * 8;
      *(uint4*)&Bs[rr][c8] = *(const uint4*)(BT + (size_t)(n0 + rr) * Kd + k0 + c8);
    }
    __syncthreads();
    bf16x8 af[4], bfr[4];
    #pragma unroll
    for (int mi = 0; mi < 4; mi++) af[mi] = *(const bf16x8*)&As[wr + mi * 16 + lr][kg];
    #pragma unroll
    for (int ni = 0; ni < 4; ni++) bfr[ni] = *(const bf16x8*)&Bs[wc + ni * 16 + lr][kg];
    #pragma unroll
    for (int mi = 0; mi < 4; mi++){
      #pragma unroll
      for (int ni = 0; ni < 4; ni++){
        acc[mi][ni] = __builtin_amdgcn_mfma_f32_16x16x32_bf16(af[mi], bfr[ni], acc[mi][ni], 0, 0, 0);
      }
    }
  }

  int rowb = m0 + wr + (lane >> 4) * 4;
  int colb = n0 + wc + lr;
  #pragma unroll
  for (int mi = 0; mi < 4; mi++){
    #pragma unroll
    for (int ni = 0; ni < 4; ni++){
      int gcol = colb + ni * 16;
      #pragma unroll
      for (int i = 0; i < 4; i++){
        int grow = rowb + mi * 16 + i;
        float xv = acc[mi][ni][i];
        size_t o = (size_t)grow * Nc + gcol;
        if (ACT == 3){ float rl = fmaxf(xv, 0.f); ((u16*)outp)[o] = f2bfr(rl * rl); }
        else outF[o] += xv;
      }
    }
  }
}

// ---------------- RWKV7 recurrence + groupnorm + gate (all fp32) ----------------
// yg may alias rbuf (in-place): r[idx] is read before yg[idx] is written.
__global__ __launch_bounds__(64) void k_rwkv(const float* rbuf, const float* __restrict__ wbuf,
                                             const float* __restrict__ kbuf, const float* __restrict__ vbuf,
                                             const float* __restrict__ abuf, const float* __restrict__ gbuf,
                                             const float* __restrict__ gng, const float* __restrict__ gnb,
                                             float* yg){
  int nh = blockIdx.x;
  int n = nh / HH, hh = nh - n * HH;
  int lane = threadIdx.x;
  float S[64];
  #pragma unroll
  for (int i = 0; i < 64; i++) S[i] = 0.f;
  int dcol = hh * KD + lane;
  float gscale = gng[dcol], gshift = gnb[dcol];
  size_t base = (size_t)n * T * D + dcol;
  for (int t = 0; t < T; t++){
    size_t idx = base + (size_t)t * D;
    float rl = rbuf[idx];
    float wl = wbuf[idx];
    float kl = kbuf[idx];
    float vl = vbuf[idx];
    float al = abuf[idx];
    float gv = gbuf[idx];
    float ss = kl * kl;
    #pragma unroll
    for (int o = 32; o; o >>= 1) ss += __shfl_xor(ss, o);
    float kkl = kl / (sqrtf(ss) + 1e-6f);
    float kal = kkl * al;
    float sa = 0.f;
    #pragma unroll
    for (int j = 0; j < 64; j++){
      S[j] = S[j] * __shfl(wl, j);
      sa += S[j] * __shfl(kkl, j);
    }
    float y = 0.f;
    #pragma unroll
    for (int j = 0; j < 64; j++){
      S[j] += vl * __shfl(kl, j) - sa * __shfl(kal, j);
      y += S[j] * __shfl(rl, j);
    }
    float s1 = y, s2 = y * y;
    #pragma unroll
    for (int o = 32; o; o >>= 1){ s1 += __shfl_xor(s1, o); s2 += __shfl_xor(s2, o); }
    float mean = s1 * (1.f / 64.f);
    float var = s2 * (1.f / 64.f) - mean * mean;
    float yn = (y - mean) * rsqrtf(var + 64e-5f);
    yg[idx] = (yn * gscale + gshift) * gv;
  }
}

// ---------------- final projection h @ W_proj + b_proj -> out fp32 ----------------
__global__ __launch_bounds__(64) void k_proj(const float* __restrict__ Hb, const float* __restrict__ Wp,
                                             const float* __restrict__ bp, float* __restrict__ out){
  int row = blockIdx.x, lane = threadIdx.x;
  int p = lane & 15, q = lane >> 4;
  const float* hr = Hb + (size_t)row * D;
  float acc = 0.f;
  #pragma unroll 8
  for (int i = 0; i < 192; i++){
    int d = q * 192 + i;
    acc += hr[d] * Wp[d * PP + p];
  }
  acc += __shfl_xor(acc, 16);
  acc += __shfl_xor(acc, 32);
  if (q == 0) out[(size_t)row * PP + p] = acc + bp[p];
}

extern "C" void kernel_launch(void* const* d_in, const int* in_sizes, int n_in,
                              void* d_out, int out_size, void* d_ws, size_t ws_size,
                              hipStream_t stream){
  (void)in_sizes; (void)n_in; (void)out_size;
  const float* x       = (const float*)d_in[0];
  const float* W_patch = (const float*)d_in[1];
  const float* b_patch = (const float*)d_in[2];
  const float* ln1_g   = (const float*)d_in[3];
  const float* ln1_b   = (const float*)d_in[4];
  const float* ln2_g   = (const float*)d_in[5];
  const float* ln2_b   = (const float*)d_in[6];
  const float* mu_r    = (const float*)d_in[7];
  const float* mu_w    = (const float*)d_in[8];
  const float* mu_k    = (const float*)d_in[9];
  const float* mu_v    = (const float*)d_in[10];
  const float* mu_a    = (const float*)d_in[11];
  const float* mu_g    = (const float*)d_in[12];
  const float* mu_c    = (const float*)d_in[13];
  const float* Wr      = (const float*)d_in[14];
  const float* Wk      = (const float*)d_in[15];
  const float* Wv      = (const float*)d_in[16];
  const float* Wg      = (const float*)d_in[17];
  const float* Ww      = (const float*)d_in[18];
  const float* w0      = (const float*)d_in[19];
  const float* Wa      = (const float*)d_in[20];
  const float* a0      = (const float*)d_in[21];
  const float* Wo      = (const float*)d_in[22];
  const float* gn_g    = (const float*)d_in[23];
  const float* gn_b    = (const float*)d_in[24];
  const float* Wc1     = (const float*)d_in[25];
  const float* Wc2     = (const float*)d_in[26];
  const float* W_proj  = (const float*)d_in[27];
  const float* b_proj  = (const float*)d_in[28];
  float* out = (float*)d_out;

  char* ws = (char*)d_ws;
  size_t off = 0;
  auto alloc = [&](size_t bytes) -> char* {
    char* p = ws + off;
    off = (off + bytes + 255) & ~(size_t)255;
    return p;
  };

  // --- static region: split bf16 weights (6 mixing) + single (Wo,Wc1,Wc2) + pe (~24 MB) ---
  const size_t WB = (size_t)D * D * 2;
  u16* WrTh = (u16*)alloc(WB); u16* WrTl = (u16*)alloc(WB);
  u16* WkTh = (u16*)alloc(WB); u16* WkTl = (u16*)alloc(WB);
  u16* WvTh = (u16*)alloc(WB); u16* WvTl = (u16*)alloc(WB);
  u16* WgTh = (u16*)alloc(WB); u16* WgTl = (u16*)alloc(WB);
  u16* WwTh = (u16*)alloc(WB); u16* WwTl = (u16*)alloc(WB);
  u16* WaTh = (u16*)alloc(WB); u16* WaTl = (u16*)alloc(WB);
  u16* WoT  = (u16*)alloc(WB);
  u16* Wc1T = (u16*)alloc((size_t)D * DFF * 2);
  u16* Wc2T = (u16*)alloc((size_t)DFF * D * 2);
  float* pe = (float*)alloc((size_t)T * D * 4);
  size_t wend = off;

  // --- choose chunking so the dynamic region fits ws_size ---
  // per chunk: 8 fp32 [Mc][768] buffers: h, xx, r, w, k, v, a, g.
  // FFN mid bf16 [Mc][3072] aliases w+k (2 fp32 buffers). yg in-place into r.
  int nch = 1;
  size_t Mc = MROWS;
  while (nch < 128){
    size_t need = wend + 8 * (Mc * 768 * 4) + 32 * 256;
    if (need <= ws_size) break;
    nch *= 2;
    Mc >>= 1;
  }
  float* hbuf = (float*)alloc(Mc * 768 * 4);
  float* xxf  = (float*)alloc(Mc * 768 * 4);
  float* rb   = (float*)alloc(Mc * 768 * 4);
  float* wb   = (float*)alloc(Mc * 768 * 4);
  float* kb   = (float*)alloc(Mc * 768 * 4);
  float* vb   = (float*)alloc(Mc * 768 * 4);
  float* ab   = (float*)alloc(Mc * 768 * 4);
  float* gb   = (float*)alloc(Mc * 768 * 4);
  u16* mid = (u16*)wb;   // spans wb..kb (Mc*3072 bf16 = Mc*6144 B = 2 fp32 buffers)

  // --- one-time prep ---
  dim3 tb(32, 8);
  k_transpose2<<<dim3(24, 24), tb, 0, stream>>>(Wr, WrTh, WrTl, D, D);
  k_transpose2<<<dim3(24, 24), tb, 0, stream>>>(Wk, WkTh, WkTl, D, D);
  k_transpose2<<<dim3(24, 24), tb, 0, stream>>>(Wv, WvTh, WvTl, D, D);
  k_transpose2<<<dim3(24, 24), tb, 0, stream>>>(Wg, WgTh, WgTl, D, D);
  k_transpose2<<<dim3(24, 24), tb, 0, stream>>>(Ww, WwTh, WwTl, D, D);
  k_transpose2<<<dim3(24, 24), tb, 0, stream>>>(Wa, WaTh, WaTl, D, D);
  k_transpose<<<dim3(24, 24), tb, 0, stream>>>(Wo, WoT, D, D);
  k_transpose<<<dim3(96, 24), tb, 0, stream>>>(Wc1, Wc1T, D, DFF);
  k_transpose<<<dim3(24, 96), tb, 0, stream>>>(Wc2, Wc2T, DFF, D);
  k_pe<<<dim3(192), dim3(256), 0, stream>>>(pe);

  // --- per-chunk pipeline (sequence-local everywhere) ---
  for (int c = 0; c < nch; ++c){
    const float* xc = x + (size_t)c * Mc * PP;
    float* outc = out + (size_t)c * Mc * PP;
    int mcb = (int)(Mc / 128);
    dim3 gg(mcb, D / 128);

    k_patch<<<dim3((int)Mc), dim3(256), 0, stream>>>(xc, W_patch, b_patch, pe, hbuf);
    k_ln<<<dim3((int)(Mc / 4)), dim3(256), 0, stream>>>(hbuf, ln1_g, ln1_b, xxf);

    k_gemm_split<0><<<gg, 256, 0, stream>>>(xxf, WrTh, WrTl, mu_r, nullptr, rb, D, D);
    k_gemm_split<1><<<gg, 256, 0, stream>>>(xxf, WwTh, WwTl, mu_w, w0,      wb, D, D);
    k_gemm_split<0><<<gg, 256, 0, stream>>>(xxf, WkTh, WkTl, mu_k, nullptr, kb, D, D);
    k_gemm_split<0><<<gg, 256, 0, stream>>>(xxf, WvTh, WvTl, mu_v, nullptr, vb, D, D);
    k_gemm_split<2><<<gg, 256, 0, stream>>>(xxf, WaTh, WaTl, mu_a, a0,      ab, D, D);
    k_gemm_split<2><<<gg, 256, 0, stream>>>(xxf, WgTh, WgTl, mu_g, nullptr, gb, D, D);

    k_rwkv<<<dim3((int)(Mc / T) * HH), dim3(64), 0, stream>>>(rb, wb, kb, vb, ab, gb, gn_g, gn_b, rb);

    k_gemm<4, true><<<gg, 256, 0, stream>>>(rb, WoT, nullptr, nullptr, hbuf, D, D);

    k_ln<<<dim3((int)(Mc / 4)), dim3(256), 0, stream>>>(hbuf, ln2_g, ln2_b, xxf);
    k_gemm<3, true><<<dim3(mcb, DFF / 128), 256, 0, stream>>>(xxf, Wc1T, mu_c, mid, nullptr, D, DFF);
    k_gemm<4, false><<<gg, 256, 0, stream>>>(mid, Wc2T, nullptr, nullptr, hbuf, DFF, D);

    k_proj<<<dim3((int)Mc), dim3(64), 0, stream>>>(hbuf, W_proj, b_proj, outc);
  }
}

// Round 5
// 2535.173 us; speedup vs baseline: 2.0402x; 2.0402x over previous
//
#include <hip/hip_runtime.h>
#include <hip/hip_bf16.h>
#include <math.h>

typedef unsigned short u16;
typedef unsigned int u32;
typedef short bf16x8 __attribute__((ext_vector_type(8)));
typedef short s16x4 __attribute__((ext_vector_type(4)));
typedef float f32x4 __attribute__((ext_vector_type(4)));

#define DEV static __device__ __forceinline__

constexpr int D = 768;
constexpr int HH = 12;
constexpr int KD = 64;
constexpr int T = 64;
constexpr int NSEQ = 512;
constexpr int MROWS = NSEQ * T;   // 32768
constexpr int DFF = 3072;
constexpr int PP = 16;

DEV float bfr2f(u16 u){ union{u32 i; float f;} c; c.i = ((u32)u) << 16; return c.f; }
DEV u16 f2bfr(float f){
  union{float f; u32 i;} c; c.f = f;
  u32 r = c.i + 0x7FFFu + ((c.i >> 16) & 1u);   // round-nearest-even
  return (u16)(r >> 16);
}
DEV float lanebc(float x, int l){ return __int_as_float(__builtin_amdgcn_readlane(__float_as_int(x), l)); }
DEV void gld_lds16(const u16* g, u16* l){
  __builtin_amdgcn_global_load_lds((const __attribute__((address_space(1))) void*)g,
                                   (__attribute__((address_space(3))) void*)l, 16, 0, 0);
}

// ---------------- transpose fp32 [R][C] -> bf16 [C][R] (single) ----------------
__global__ __launch_bounds__(256) void k_transpose(const float* __restrict__ W, u16* __restrict__ WT,
                                                   int R, int C){
  __shared__ float tile[32][33];
  int c0 = blockIdx.x * 32, r0 = blockIdx.y * 32;
  int tx = threadIdx.x, ty = threadIdx.y;
  #pragma unroll
  for (int i = 0; i < 32; i += 8)
    tile[ty + i][tx] = W[(size_t)(r0 + ty + i) * C + (c0 + tx)];
  __syncthreads();
  #pragma unroll
  for (int i = 0; i < 32; i += 8)
    WT[(size_t)(c0 + ty + i) * R + (r0 + tx)] = f2bfr(tile[tx][ty + i]);
}

// ---------------- transpose fp32 [R][C] -> split bf16 hi/lo [C][R] ----------------
__global__ __launch_bounds__(256) void k_transpose2(const float* __restrict__ W, u16* __restrict__ WTh,
                                                    u16* __restrict__ WTl, int R, int C){
  __shared__ float tile[32][33];
  int c0 = blockIdx.x * 32, r0 = blockIdx.y * 32;
  int tx = threadIdx.x, ty = threadIdx.y;
  #pragma unroll
  for (int i = 0; i < 32; i += 8)
    tile[ty + i][tx] = W[(size_t)(r0 + ty + i) * C + (c0 + tx)];
  __syncthreads();
  #pragma unroll
  for (int i = 0; i < 32; i += 8){
    float v = tile[tx][ty + i];
    u16 hi = f2bfr(v);
    float rem = v - bfr2f(hi);
    size_t o = (size_t)(c0 + ty + i) * R + (r0 + tx);
    WTh[o] = hi;
    WTl[o] = f2bfr(rem);
  }
}

// ---------------- positional embedding [T][D] ----------------
__global__ void k_pe(float* __restrict__ pe){
  int idx = blockIdx.x * 256 + threadIdx.x;
  if (idx >= T * D) return;
  int t = idx / D, d = idx % D;
  float dv = __expf((float)(d & ~1) * (-9.210340371976184f / (float)D));
  float ang = (float)t * dv;
  pe[idx] = (d & 1) ? cosf(ang) : sinf(ang);
}

// ---------------- patch embedding: h = patches @ W_patch + b + pe ----------------
__global__ __launch_bounds__(256) void k_patch(const float* __restrict__ x, const float* __restrict__ Wp,
                                               const float* __restrict__ bp, const float* __restrict__ pe,
                                               float* __restrict__ h){
  int row = blockIdx.x, t = row & (T - 1);
  __shared__ float xs[PP];
  if (threadIdx.x < PP) xs[threadIdx.x] = x[(size_t)row * PP + threadIdx.x];
  __syncthreads();
  #pragma unroll
  for (int j = 0; j < 3; j++){
    int d = threadIdx.x + j * 256;
    float acc = bp[d] + pe[t * D + d];
    #pragma unroll
    for (int p = 0; p < PP; p++) acc += xs[p] * Wp[p * D + d];
    h[(size_t)row * D + d] = acc;
  }
}

// ---------------- layernorm fp32 -> fp32 ----------------
__global__ __launch_bounds__(256) void k_ln(const float* __restrict__ X, const float* __restrict__ g,
                                            const float* __restrict__ b, float* __restrict__ out){
  int lane = threadIdx.x & 63;
  int row = blockIdx.x * 4 + (threadIdx.x >> 6);
  const float* xr = X + (size_t)row * D;
  float v[12], s = 0.f, sq = 0.f;
  #pragma unroll
  for (int j = 0; j < 12; j++){ v[j] = xr[lane + j * 64]; s += v[j]; sq += v[j] * v[j]; }
  #pragma unroll
  for (int o = 32; o; o >>= 1){ s += __shfl_xor(s, o); sq += __shfl_xor(sq, o); }
  float mean = s * (1.f / 768.f);
  float rstd = rsqrtf(sq * (1.f / 768.f) - mean * mean + 1e-5f);
  float* orow = out + (size_t)row * D;
  #pragma unroll
  for (int j = 0; j < 12; j++){
    int d = lane + j * 64;
    orow[d] = (v[j] - mean) * rstd * g[d] + b[d];
  }
}

// ---------------- LN2 + token-shift lerp fused -> bf16 xk ----------------
__global__ __launch_bounds__(256) void k_ln2(const float* __restrict__ X, const float* __restrict__ g,
                                             const float* __restrict__ b, const float* __restrict__ mu,
                                             u16* __restrict__ out){
  int lane = threadIdx.x & 63;
  int row = blockIdx.x * 4 + (threadIdx.x >> 6);
  int t = row & (T - 1);
  const float* xr = X + (size_t)row * D;
  float v[12], s = 0.f, sq = 0.f;
  #pragma unroll
  for (int j = 0; j < 12; j++){ v[j] = xr[lane + j * 64]; s += v[j]; sq += v[j] * v[j]; }
  #pragma unroll
  for (int o = 32; o; o >>= 1){ s += __shfl_xor(s, o); sq += __shfl_xor(sq, o); }
  float mean = s * (1.f / 768.f);
  float rstd = rsqrtf(sq * (1.f / 768.f) - mean * mean + 1e-5f);
  float p[12], meanp = 0.f, rstdp = 0.f;
  if (t){
    const float* xp = xr - D;
    float sp = 0.f, sqp = 0.f;
    #pragma unroll
    for (int j = 0; j < 12; j++){ p[j] = xp[lane + j * 64]; sp += p[j]; sqp += p[j] * p[j]; }
    #pragma unroll
    for (int o = 32; o; o >>= 1){ sp += __shfl_xor(sp, o); sqp += __shfl_xor(sqp, o); }
    meanp = sp * (1.f / 768.f);
    rstdp = rsqrtf(sqp * (1.f / 768.f) - meanp * meanp + 1e-5f);
  }
  u16* orow = out + (size_t)row * D;
  #pragma unroll
  for (int j = 0; j < 12; j++){
    int d = lane + j * 64;
    float cm = (v[j] - mean) * rstd * g[d] + b[d];
    float cp = t ? (p[j] - meanp) * rstdp * g[d] + b[d] : 0.f;
    orow[d] = f2bfr(cm + (cp - cm) * mu[d]);
  }
}

// ---------------- batched split-bf16 mixing GEMM (6 outputs) ----------------
// A fp32 [M][768]; per-z: token-shift lerp (fp32) at staging, split hi/lo, 3-product MFMA.
// z: 0 r(ACT0) 1 w(ACT1,w0) 2 k(ACT0) 3 v(ACT0) 4 a(ACT2,a0) 5 g(ACT2)
struct MixArgs {
  const u16* bh[6]; const u16* bl[6];
  const float* mu[6]; const float* bias[6];
  float* out[6];
};
__global__ __launch_bounds__(256) void k_gemm_mix(const float* __restrict__ A, MixArgs args, int Kd, int Nc){
  __shared__ __align__(16) u16 Ah[128][40];
  __shared__ __align__(16) u16 Al[128][40];
  __shared__ __align__(16) u16 Bh[128][40];
  __shared__ __align__(16) u16 Bl[128][40];
  int tid = threadIdx.x;
  int z = blockIdx.z;
  int m0 = blockIdx.x * 128, n0 = blockIdx.y * 128;
  const u16* BTh = args.bh[z];
  const u16* BTl = args.bl[z];
  const float* mu = args.mu[z];
  const float* bias = args.bias[z];
  float* outp = args.out[z];
  int wv = tid >> 6, lane = tid & 63;
  int wr = (wv >> 1) * 64, wc = (wv & 1) * 64;
  int lr = lane & 15, kg = (lane >> 4) * 8;
  f32x4 acc[4][4] = {};

  for (int k0 = 0; k0 < Kd; k0 += 32){
    __syncthreads();
    #pragma unroll
    for (int pass = 0; pass < 4; pass++){
      int c = pass * 256 + tid;
      int rr = c >> 3, c4 = (c & 7) * 4;
      const float* srcA = A + (size_t)(m0 + rr) * Kd + k0 + c4;
      float4 cur = *(const float4*)srcA;
      bool tnz = ((m0 + rr) & (T - 1)) != 0;
      float4 prv = tnz ? *(const float4*)(srcA - Kd) : make_float4(0.f, 0.f, 0.f, 0.f);
      float* cf = (float*)&cur; float* pf = (float*)&prv;
      s16x4 ph, pl;
      #pragma unroll
      for (int j = 0; j < 4; j++){
        float m = mu[k0 + c4 + j];
        float val = cf[j] + (pf[j] - cf[j]) * m;
        u16 hi = f2bfr(val);
        ph[j] = (short)hi;
        pl[j] = (short)f2bfr(val - bfr2f(hi));
      }
      *(s16x4*)&Ah[rr][c4] = ph;
      *(s16x4*)&Al[rr][c4] = pl;
    }
    #pragma unroll
    for (int pass = 0; pass < 2; pass++){
      int c = pass * 256 + tid;
      int rr = c >> 2, c8 = (c & 3) * 8;
      size_t o = (size_t)(n0 + rr) * Kd + k0 + c8;
      *(uint4*)&Bh[rr][c8] = *(const uint4*)(BTh + o);
      *(uint4*)&Bl[rr][c8] = *(const uint4*)(BTl + o);
    }
    __syncthreads();
    bf16x8 ah[4], al[4], bh[4], bl[4];
    #pragma unroll
    for (int mi = 0; mi < 4; mi++){
      ah[mi] = *(const bf16x8*)&Ah[wr + mi * 16 + lr][kg];
      al[mi] = *(const bf16x8*)&Al[wr + mi * 16 + lr][kg];
    }
    #pragma unroll
    for (int ni = 0; ni < 4; ni++){
      bh[ni] = *(const bf16x8*)&Bh[wc + ni * 16 + lr][kg];
      bl[ni] = *(const bf16x8*)&Bl[wc + ni * 16 + lr][kg];
    }
    #pragma unroll
    for (int mi = 0; mi < 4; mi++){
      #pragma unroll
      for (int ni = 0; ni < 4; ni++){
        acc[mi][ni] = __builtin_amdgcn_mfma_f32_16x16x32_bf16(ah[mi], bh[ni], acc[mi][ni], 0, 0, 0);
        acc[mi][ni] = __builtin_amdgcn_mfma_f32_16x16x32_bf16(al[mi], bh[ni], acc[mi][ni], 0, 0, 0);
        acc[mi][ni] = __builtin_amdgcn_mfma_f32_16x16x32_bf16(ah[mi], bl[ni], acc[mi][ni], 0, 0, 0);
      }
    }
  }

  int actz = (z == 1) ? 1 : (z >= 4 ? 2 : 0);
  int rowb = m0 + wr + (lane >> 4) * 4;
  int colb = n0 + wc + lr;
  #pragma unroll
  for (int mi = 0; mi < 4; mi++){
    #pragma unroll
    for (int ni = 0; ni < 4; ni++){
      int gcol = colb + ni * 16;
      float bv = (actz != 0 && bias) ? bias[gcol] : 0.f;
      #pragma unroll
      for (int i = 0; i < 4; i++){
        int grow = rowb + mi * 16 + i;
        float xv = acc[mi][ni][i] + bv;
        size_t o = (size_t)grow * Nc + gcol;
        if (actz == 0)      outp[o] = xv;
        else if (actz == 1) outp[o] = __expf(-__expf(xv));
        else                outp[o] = 1.f / (1.f + __expf(-xv));
      }
    }
  }
}

// ---------------- m97-style single-bf16 GEMM: pure-copy A/B via global_load_lds ----------------
// A bf16 [M][Kd], BT bf16 [Nc][Kd]. ACT: 3 relu^2->bf16 outB, 4 add->fp32 outF
template<int ACT>
__global__ __launch_bounds__(256) void k_gemm97(const u16* __restrict__ A, const u16* __restrict__ BT,
                                                u16* __restrict__ outB, float* __restrict__ outF,
                                                int Kd, int Nc){
  __shared__ __align__(16) u16 As[128 * 32];
  __shared__ __align__(16) u16 Bs[128 * 32];
  int tid = threadIdx.x;
  int m0 = blockIdx.x * 128, n0 = blockIdx.y * 128;
  int wv = tid >> 6, lane = tid & 63;
  int wr = (wv >> 1) * 64, wc = (wv & 1) * 64;
  int lr = lane & 15, kg = (lane >> 4) * 8;
  // staging map: issue i in {0,1}: LDS row = wv*16 + lane/4 + i*64, col = (lane&3)*8 elems
  int r0 = wv * 16 + (lane >> 2);
  int cb = (lane & 3) * 8;
  const u16* sA0 = A + (size_t)(m0 + r0) * Kd + cb;
  const u16* sA1 = A + (size_t)(m0 + r0 + 64) * Kd + cb;
  const u16* sB0 = BT + (size_t)(n0 + r0) * Kd + cb;
  const u16* sB1 = BT + (size_t)(n0 + r0 + 64) * Kd + cb;
  u16* dA0 = As + r0 * 32 + cb;
  u16* dA1 = As + (r0 + 64) * 32 + cb;
  u16* dB0 = Bs + r0 * 32 + cb;
  u16* dB1 = Bs + (r0 + 64) * 32 + cb;
  f32x4 acc[4][4] = {};

  for (int k0 = 0; k0 < Kd; k0 += 32){
    __syncthreads();
    gld_lds16(sA0 + k0, dA0);
    gld_lds16(sA1 + k0, dA1);
    gld_lds16(sB0 + k0, dB0);
    gld_lds16(sB1 + k0, dB1);
    __syncthreads();
    bf16x8 af[4], bfr[4];
    #pragma unroll
    for (int mi = 0; mi < 4; mi++) af[mi] = *(const bf16x8*)&As[(wr + mi * 16 + lr) * 32 + kg];
    #pragma unroll
    for (int ni = 0; ni < 4; ni++) bfr[ni] = *(const bf16x8*)&Bs[(wc + ni * 16 + lr) * 32 + kg];
    #pragma unroll
    for (int mi = 0; mi < 4; mi++){
      #pragma unroll
      for (int ni = 0; ni < 4; ni++){
        acc[mi][ni] = __builtin_amdgcn_mfma_f32_16x16x32_bf16(af[mi], bfr[ni], acc[mi][ni], 0, 0, 0);
      }
    }
  }

  int rowb = m0 + wr + (lane >> 4) * 4;
  int colb = n0 + wc + lr;
  #pragma unroll
  for (int mi = 0; mi < 4; mi++){
    #pragma unroll
    for (int ni = 0; ni < 4; ni++){
      int gcol = colb + ni * 16;
      #pragma unroll
      for (int i = 0; i < 4; i++){
        int grow = rowb + mi * 16 + i;
        float xv = acc[mi][ni][i];
        size_t o = (size_t)grow * Nc + gcol;
        if (ACT == 3){ float rl = fmaxf(xv, 0.f); outB[o] = f2bfr(rl * rl); }
        else outF[o] += xv;
      }
    }
  }
}

// ---------------- RWKV7 recurrence + groupnorm + gate (fp32, readlane broadcasts) ----------------
__global__ __launch_bounds__(64) void k_rwkv(const float* __restrict__ rbuf, const float* __restrict__ wbuf,
                                             const float* __restrict__ kbuf, const float* __restrict__ vbuf,
                                             const float* __restrict__ abuf, const float* __restrict__ gbuf,
                                             const float* __restrict__ gng, const float* __restrict__ gnb,
                                             u16* __restrict__ yg){
  int nh = blockIdx.x;
  int n = nh / HH, hh = nh - n * HH;
  int lane = threadIdx.x;
  float S[64];
  #pragma unroll
  for (int i = 0; i < 64; i++) S[i] = 0.f;
  int dcol = hh * KD + lane;
  float gscale = gng[dcol], gshift = gnb[dcol];
  size_t base = (size_t)n * T * D + dcol;
  for (int t = 0; t < T; t++){
    size_t idx = base + (size_t)t * D;
    float rl = rbuf[idx];
    float wl = wbuf[idx];
    float kl = kbuf[idx];
    float vl = vbuf[idx];
    float al = abuf[idx];
    float gv = gbuf[idx];
    float ss = kl * kl;
    #pragma unroll
    for (int o = 32; o; o >>= 1) ss += __shfl_xor(ss, o);
    float kkl = kl / (sqrtf(ss) + 1e-6f);
    float kal = kkl * al;
    float sa = 0.f;
    #pragma unroll
    for (int j = 0; j < 64; j++){
      S[j] = S[j] * lanebc(wl, j);
      sa += S[j] * lanebc(kkl, j);
    }
    float y = 0.f;
    #pragma unroll
    for (int j = 0; j < 64; j++){
      S[j] += vl * lanebc(kl, j) - sa * lanebc(kal, j);
      y += S[j] * lanebc(rl, j);
    }
    float s1 = y, s2 = y * y;
    #pragma unroll
    for (int o = 32; o; o >>= 1){ s1 += __shfl_xor(s1, o); s2 += __shfl_xor(s2, o); }
    float mean = s1 * (1.f / 64.f);
    float var = s2 * (1.f / 64.f) - mean * mean;
    float yn = (y - mean) * rsqrtf(var + 64e-5f);
    yg[idx] = f2bfr((yn * gscale + gshift) * gv);
  }
}

// ---------------- final projection h @ W_proj + b_proj -> out fp32 ----------------
__global__ __launch_bounds__(64) void k_proj(const float* __restrict__ Hb, const float* __restrict__ Wp,
                                             const float* __restrict__ bp, float* __restrict__ out){
  int row = blockIdx.x, lane = threadIdx.x;
  int p = lane & 15, q = lane >> 4;
  const float* hr = Hb + (size_t)row * D;
  float acc = 0.f;
  #pragma unroll 8
  for (int i = 0; i < 192; i++){
    int d = q * 192 + i;
    acc += hr[d] * Wp[d * PP + p];
  }
  acc += __shfl_xor(acc, 16);
  acc += __shfl_xor(acc, 32);
  if (q == 0) out[(size_t)row * PP + p] = acc + bp[p];
}

extern "C" void kernel_launch(void* const* d_in, const int* in_sizes, int n_in,
                              void* d_out, int out_size, void* d_ws, size_t ws_size,
                              hipStream_t stream){
  (void)in_sizes; (void)n_in; (void)out_size;
  const float* x       = (const float*)d_in[0];
  const float* W_patch = (const float*)d_in[1];
  const float* b_patch = (const float*)d_in[2];
  const float* ln1_g   = (const float*)d_in[3];
  const float* ln1_b   = (const float*)d_in[4];
  const float* ln2_g   = (const float*)d_in[5];
  const float* ln2_b   = (const float*)d_in[6];
  const float* mu_r    = (const float*)d_in[7];
  const float* mu_w    = (const float*)d_in[8];
  const float* mu_k    = (const float*)d_in[9];
  const float* mu_v    = (const float*)d_in[10];
  const float* mu_a    = (const float*)d_in[11];
  const float* mu_g    = (const float*)d_in[12];
  const float* mu_c    = (const float*)d_in[13];
  const float* Wr      = (const float*)d_in[14];
  const float* Wk      = (const float*)d_in[15];
  const float* Wv      = (const float*)d_in[16];
  const float* Wg      = (const float*)d_in[17];
  const float* Ww      = (const float*)d_in[18];
  const float* w0      = (const float*)d_in[19];
  const float* Wa      = (const float*)d_in[20];
  const float* a0      = (const float*)d_in[21];
  const float* Wo      = (const float*)d_in[22];
  const float* gn_g    = (const float*)d_in[23];
  const float* gn_b    = (const float*)d_in[24];
  const float* Wc1     = (const float*)d_in[25];
  const float* Wc2     = (const float*)d_in[26];
  const float* W_proj  = (const float*)d_in[27];
  const float* b_proj  = (const float*)d_in[28];
  float* out = (float*)d_out;

  char* ws = (char*)d_ws;
  size_t off = 0;
  auto alloc = [&](size_t bytes) -> char* {
    char* p = ws + off;
    off = (off + bytes + 255) & ~(size_t)255;
    return p;
  };

  // --- static region: split bf16 weights (6 mixing) + single (Wo,Wc1,Wc2) + pe (~24 MB) ---
  const size_t WB = (size_t)D * D * 2;
  u16* WrTh = (u16*)alloc(WB); u16* WrTl = (u16*)alloc(WB);
  u16* WkTh = (u16*)alloc(WB); u16* WkTl = (u16*)alloc(WB);
  u16* WvTh = (u16*)alloc(WB); u16* WvTl = (u16*)alloc(WB);
  u16* WgTh = (u16*)alloc(WB); u16* WgTl = (u16*)alloc(WB);
  u16* WwTh = (u16*)alloc(WB); u16* WwTl = (u16*)alloc(WB);
  u16* WaTh = (u16*)alloc(WB); u16* WaTl = (u16*)alloc(WB);
  u16* WoT  = (u16*)alloc(WB);
  u16* Wc1T = (u16*)alloc((size_t)D * DFF * 2);
  u16* Wc2T = (u16*)alloc((size_t)DFF * D * 2);
  float* pe = (float*)alloc((size_t)T * D * 4);
  size_t wend = off;

  // --- chunking: per chunk 8 fp32 [Mc][768] + ygb bf16 [Mc][768] ---
  // mid bf16 [Mc][3072] aliases wb+kb; xk bf16 [Mc][768] aliases xxf.
  int nch = 1;
  size_t Mc = MROWS;
  while (nch < 128){
    size_t need = wend + Mc * (8 * 3072 + 1536) + 64 * 256;
    if (need <= ws_size) break;
    nch *= 2;
    Mc >>= 1;
  }
  float* hbuf = (float*)alloc(Mc * 768 * 4);
  float* xxf  = (float*)alloc(Mc * 768 * 4);
  float* rb   = (float*)alloc(Mc * 768 * 4);
  float* wb   = (float*)alloc(Mc * 768 * 4);
  float* kb   = (float*)alloc(Mc * 768 * 4);
  float* vb   = (float*)alloc(Mc * 768 * 4);
  float* ab   = (float*)alloc(Mc * 768 * 4);
  float* gb   = (float*)alloc(Mc * 768 * 4);
  u16* ygb    = (u16*)alloc(Mc * 768 * 2);
  u16* mid = (u16*)wb;   // spans wb..kb (Mc*3072 bf16 = 2 fp32 buffers)
  u16* xkb = (u16*)xxf;  // xxf dead after mixing GEMMs

  // --- one-time prep ---
  dim3 tb(32, 8);
  k_transpose2<<<dim3(24, 24), tb, 0, stream>>>(Wr, WrTh, WrTl, D, D);
  k_transpose2<<<dim3(24, 24), tb, 0, stream>>>(Wk, WkTh, WkTl, D, D);
  k_transpose2<<<dim3(24, 24), tb, 0, stream>>>(Wv, WvTh, WvTl, D, D);
  k_transpose2<<<dim3(24, 24), tb, 0, stream>>>(Wg, WgTh, WgTl, D, D);
  k_transpose2<<<dim3(24, 24), tb, 0, stream>>>(Ww, WwTh, WwTl, D, D);
  k_transpose2<<<dim3(24, 24), tb, 0, stream>>>(Wa, WaTh, WaTl, D, D);
  k_transpose<<<dim3(24, 24), tb, 0, stream>>>(Wo, WoT, D, D);
  k_transpose<<<dim3(96, 24), tb, 0, stream>>>(Wc1, Wc1T, D, DFF);
  k_transpose<<<dim3(24, 96), tb, 0, stream>>>(Wc2, Wc2T, DFF, D);
  k_pe<<<dim3(192), dim3(256), 0, stream>>>(pe);

  MixArgs margs;
  margs.bh[0] = WrTh; margs.bl[0] = WrTl; margs.mu[0] = mu_r; margs.bias[0] = nullptr; margs.out[0] = rb;
  margs.bh[1] = WwTh; margs.bl[1] = WwTl; margs.mu[1] = mu_w; margs.bias[1] = w0;      margs.out[1] = wb;
  margs.bh[2] = WkTh; margs.bl[2] = WkTl; margs.mu[2] = mu_k; margs.bias[2] = nullptr; margs.out[2] = kb;
  margs.bh[3] = WvTh; margs.bl[3] = WvTl; margs.mu[3] = mu_v; margs.bias[3] = nullptr; margs.out[3] = vb;
  margs.bh[4] = WaTh; margs.bl[4] = WaTl; margs.mu[4] = mu_a; margs.bias[4] = a0;      margs.out[4] = ab;
  margs.bh[5] = WgTh; margs.bl[5] = WgTl; margs.mu[5] = mu_g; margs.bias[5] = nullptr; margs.out[5] = gb;

  // --- per-chunk pipeline (sequence-local everywhere) ---
  for (int c = 0; c < nch; ++c){
    const float* xc = x + (size_t)c * Mc * PP;
    float* outc = out + (size_t)c * Mc * PP;
    int mcb = (int)(Mc / 128);

    k_patch<<<dim3((int)Mc), dim3(256), 0, stream>>>(xc, W_patch, b_patch, pe, hbuf);
    k_ln<<<dim3((int)(Mc / 4)), dim3(256), 0, stream>>>(hbuf, ln1_g, ln1_b, xxf);

    k_gemm_mix<<<dim3(mcb, 6, 6), 256, 0, stream>>>(xxf, margs, D, D);

    k_rwkv<<<dim3((int)(Mc / T) * HH), dim3(64), 0, stream>>>(rb, wb, kb, vb, ab, gb, gn_g, gn_b, ygb);

    k_gemm97<4><<<dim3(mcb, 6), 256, 0, stream>>>(ygb, WoT, nullptr, hbuf, D, D);

    k_ln2<<<dim3((int)(Mc / 4)), dim3(256), 0, stream>>>(hbuf, ln2_g, ln2_b, mu_c, xkb);
    k_gemm97<3><<<dim3(mcb, DFF / 128), 256, 0, stream>>>(xkb, Wc1T, mid, nullptr, D, DFF);
    k_gemm97<4><<<dim3(mcb, 6), 256, 0, stream>>>(mid, Wc2T, nullptr, hbuf, DFF, D);

    k_proj<<<dim3((int)Mc), dim3(64), 0, stream>>>(hbuf, W_proj, b_proj, outc);
  }
}